// Round 16
// baseline (141.745 us; speedup 1.0000x reference)
//
#include <hip/hip_runtime.h>
#include <math.h>

// Model_7310034338114: two Flaubert/XLM MHA blocks (eval), fp32 in/out.
// inst0: x (4,1024,192), 16 heads, dph=12. inst1: y (4,1024,66), 11 heads, dph=6.
//
// Round 27 = r26 (best, 138.32us) + oproj 32-row tiles ISOLATED (r16 bundled
// it with an attn change and was neutral; r23 showed the attn half was the
// likely regression). oproj: 640 blocks @ 2.5/CU, per-block path halves,
// accumulation chains unchanged -> bit-identical.
//
// qkv post-r26 status: runs ~38us at 32 waves/CU (probe occupancy) with
// stores -> occupancy DEFINITIVELY exonerated; with addressing (r20),
// scan/barriers (r24), conflicts (r17/18), dispatch (r15/16) all null, the
// stores-present delta (~33us) is in a resource invisible to our counters.
// Budget: fill 42 (harness, in-window) + qkv 38 + attn 21.6 + oproj 3.5 +
// boundaries ~31 = 138. attn VALU-bound (71%), near its structural floor.
//
// Lessons ledger: r12 grid.sync ~100us; r14 no cross-XCD fusion/threadfence;
// r15/r16 dispatch/amortization minor; r17 qkv ~40us; r18 conflict/256CUs +
// LDS-occ > barriers; r19 probe confounded by VGPR; r20 store addressing
// null; r21 3->4 blk/CU -1.4; r23 attn 21.6 VALU, oproj 3.5; r24 bias-split
// + shuffle-scan null; r25 256thr VGPR64 = spill disaster; r26 512thr
// VGPR64 ok, 32 waves/CU only -1.6 (occupancy exonerated).

#define BS 4
#define SLEN 1024

// workspace float offsets
#define Q0_OFF 0              // f32 [4][1024][192]     (786432)
#define C0_OFF 786432         // f32 [4096][192]        (786432)
#define Q1_OFF 1572864        // f32 [4][1024][66]      (270336)
#define C1_OFF 1843200        // f32 [4096][66]         (270336)
#define K0H_OFF 2113536       // f16 [4][16][1024][12]  (786432 h = 393216 fl)
#define V0T_OFF 2506752       // f16 [4][16][12][1024]  (786432 h)
#define K1H_OFF 2899968       // f16 [4][11][1024][8]   (360448 h = 180224 fl)
#define V1T_OFF 3080192       // f16 [4][11][6][1024]   (270336 h = 135168 fl)
#define CNT_OFF 3223552       // int [8] (inst*4 + b)

#define OUT0_SIZE 786432      // 4096*192

#if __has_builtin(__builtin_amdgcn_exp2f)
#define EXP2(x) __builtin_amdgcn_exp2f(x)
#else
static __device__ __forceinline__ float exp2_asm(float x) {
  float r;
  asm("v_exp_f32 %0, %1" : "=v"(r) : "v"(x));
  return r;
}
#define EXP2(x) exp2_asm(x)
#endif

typedef _Float16 f16x2 __attribute__((ext_vector_type(2)));
typedef _Float16 f16x4 __attribute__((ext_vector_type(4)));
typedef _Float16 f16x8 __attribute__((ext_vector_type(8)));
typedef float f32x4 __attribute__((ext_vector_type(4)));

// ---------------------------------------------------------------------------
// f16-MFMA GEMM building block (hi/lo split, MT m-tiles), for oproj.
// ---------------------------------------------------------------------------
template <int MT>
__device__ __forceinline__ void mfma_chunk_split(
    const _Float16* sAh, const _Float16* sAl,
    const _Float16* sWTh, const _Float16* sWTl,
    int wv, int lane, f32x4 acc[MT])
{
  const int col = lane & 15, grp = lane >> 4;
#pragma unroll
  for (int ks = 0; ks < 2; ++ks) {
    const int boff = (wv * 16 + col) * 72 + ks * 32 + grp * 8;
    const f16x8 bh = *(const f16x8*)(sWTh + boff);
    const f16x8 bl = *(const f16x8*)(sWTl + boff);
#pragma unroll
    for (int mt = 0; mt < MT; ++mt) {
      const int aoff = (mt * 16 + col) * 72 + ks * 32 + grp * 8;
      const f16x8 ah = *(const f16x8*)(sAh + aoff);
      const f16x8 al = *(const f16x8*)(sAl + aoff);
      acc[mt] = __builtin_amdgcn_mfma_f32_16x16x32_f16(ah, bh, acc[mt], 0, 0, 0);
      acc[mt] = __builtin_amdgcn_mfma_f32_16x16x32_f16(ah, bl, acc[mt], 0, 0, 0);
      acc[mt] = __builtin_amdgcn_mfma_f32_16x16x32_f16(al, bh, acc[mt], 0, 0, 0);
    }
  }
}

// ---------------------------------------------------------------------------
// QKV projection + integrated mask scan — 512-thread / 8-wave (r26).
// Wave w: col-strip (w&3), m-half (w>>2); acc[2] per wave.
// ---------------------------------------------------------------------------
template <int DIM, int H, int DPH, int NT, int NCH, int KST>
__device__ void qkv_impl(int bid, const float* __restrict__ X,
                         const int* __restrict__ mask,
                         const float* __restrict__ qw, const float* __restrict__ qb,
                         const float* __restrict__ kw, const float* __restrict__ kb,
                         const float* __restrict__ vw, const float* __restrict__ vb,
                         float* __restrict__ qo, _Float16* __restrict__ kh,
                         _Float16* __restrict__ vth, int* __restrict__ cnt_out,
                         char* smem)
{
  const int mt64 = bid & 63;
  const int rest = bid >> 6;
  const int mat = rest / NT;
  const int nt = rest % NT;
  const int row0 = mt64 * 64, col0 = nt * 64;

  const float* W = (mat == 0) ? qw : (mat == 1) ? kw : vw;
  const float* B = (mat == 0) ? qb : (mat == 1) ? kb : vb;
  const float scale = (mat == 0) ? (1.44269504089f / sqrtf((float)DPH)) : 1.0f;

  _Float16* sA = (_Float16*)smem;            // 64*72 halves
  _Float16* sWT = sA + 64 * 72;              // 64*72 halves
  int* sSP = (int*)(smem + 2 * 64 * 72 * 2); // 64 ints, persists to epilogue
  int* sW8 = sSP + 64;                       // 8 ints (wave scan totals)

  const int tid = threadIdx.x;               // 0..511
  const int wv = tid >> 6, lane = tid & 63;
  const int cs = wv & 3;                     // col strip (0..3)
  const int mh = wv >> 2;                    // m half (0..1)

  // register-staged prefetch (global->reg) / commit (reg->LDS as f16)
  float2 rA[4], rW[4];
  auto qprefetch = [&](int c) {
    const int kc = c * 64;
#pragma unroll
    for (int t = 0; t < 4; ++t) {
      const int idx = tid + t * 512;
      {
        const int m = idx >> 5, k = (idx & 31) * 2;
        rA[t] = (kc + k < DIM)
                    ? *(const float2*)(X + (size_t)(row0 + m) * DIM + kc + k)
                    : make_float2(0.f, 0.f);
      }
      {
        const int k = idx >> 5, n = (idx & 31) * 2;
        rW[t] = (kc + k < DIM && col0 + n < DIM)
                    ? *(const float2*)(W + (size_t)(kc + k) * DIM + col0 + n)
                    : make_float2(0.f, 0.f);
      }
    }
  };
  auto qcommit = [&]() {
#pragma unroll
    for (int t = 0; t < 4; ++t) {
      const int idx = tid + t * 512;
      {
        const int m = idx >> 5, k = (idx & 31) * 2;
        *(f16x2*)(sA + m * 72 + k) = (f16x2){(_Float16)rA[t].x, (_Float16)rA[t].y};
      }
      {
        const int k = idx >> 5, n = (idx & 31) * 2;
        sWT[n * 72 + k] = (_Float16)rW[t].x;
        sWT[(n + 1) * 72 + k] = (_Float16)rW[t].y;
      }
    }
  };

  qprefetch(0);   // issue chunk-0 loads first; scan below runs under their latency

  // ---- in-block mask scan (K/V blocks only): 2 keys/thread, 8-wave combine ----
  int totKV = 0;
  if (mat != 0) {
    const int b = row0 >> 10;
    const int* m = mask + (b << 10);
    int mv[2], s4 = 0;
#pragma unroll
    for (int i = 0; i < 2; ++i) { mv[i] = m[tid * 2 + i] ? 1 : 0; s4 += mv[i]; }
    int ps = s4;                       // wave64 inclusive scan, no barriers
#pragma unroll
    for (int off = 1; off < 64; off <<= 1) {
      const int v = __shfl_up(ps, off);
      if (lane >= off) ps += v;
    }
    if (lane == 63) sW8[wv] = ps;
    __syncthreads();
    int wbase = 0, tot = 0;
#pragma unroll
    for (int w = 0; w < 8; ++w) {
      const int t = sW8[w];
      tot += t;
      if (w < wv) wbase += t;
    }
    totKV = tot;
    int u = wbase + ps - s4;           // exclusive prefix of unmasked count
    const int s0 = row0 & 1023;
#pragma unroll
    for (int i = 0; i < 2; ++i) {
      const int s = tid * 2 + i;
      const int sp = mv[i] ? u : tot + (s - u);
      u += mv[i];
      const unsigned rel = (unsigned)(s - s0);
      if (rel < 64u) sSP[rel] = sp;
    }
    if (mat == 1 && nt == 0 && s0 == 0 && tid == 0) cnt_out[b] = tot;
    __syncthreads();   // sSP visible
  }

  f32x4 acc[2] = {{0.f,0.f,0.f,0.f},{0.f,0.f,0.f,0.f}};
  const int col = lane & 15, grp = lane >> 4;

  for (int c = 0; c < NCH; ++c) {
    __syncthreads();                 // previous mfma done reading LDS
    qcommit();
    __syncthreads();
    if (c + 1 < NCH) qprefetch(c + 1);   // loads overlap this chunk's MFMA
#pragma unroll
    for (int ks = 0; ks < 2; ++ks) {
      const f16x8 bf = *(const f16x8*)(sWT + (cs * 16 + col) * 72 + ks * 32 + grp * 8);
#pragma unroll
      for (int mt = 0; mt < 2; ++mt) {
        const int mtg = mh * 2 + mt;
        const f16x8 af = *(const f16x8*)(sA + (mtg * 16 + col) * 72 + ks * 32 + grp * 8);
        acc[mt] = __builtin_amdgcn_mfma_f32_16x16x32_f16(af, bf, acc[mt], 0, 0, 0);
      }
    }
  }

  const int cidx = col0 + cs * 16 + col;
  const int slim = ((totKV + 127) >> 7) << 7;   // slots >= slim never read

  if (mat == 0) {
    // Q -> [b][s][DIM]: 16 consecutive lanes hit 64B-contiguous addresses.
    if (cidx < DIM) {
      const float bias = B[cidx];
#pragma unroll
      for (int mt = 0; mt < 2; ++mt) {
        const int mtg = mh * 2 + mt;
#pragma unroll
        for (int r = 0; r < 4; ++r) {
          const int m = row0 + mtg * 16 + grp * 4 + r;   // == b*1024 + s
          qo[(size_t)m * DIM + cidx] = (acc[mt][r] + bias) * scale;
        }
      }
    }
  } else if (mat == 1) {
    // K -> [bh][sp][KST] (24B runs) + dead-slot skip.
    if (cidx < DIM) {
      const float bias = B[cidx];
      const int h = cidx / DPH, d = cidx % DPH;
#pragma unroll
      for (int mt = 0; mt < 2; ++mt) {
        const int mtg = mh * 2 + mt;
#pragma unroll
        for (int r = 0; r < 4; ++r) {
          const int m = row0 + mtg * 16 + grp * 4 + r;
          const int b = m >> 10;
          const int sp = sSP[mtg * 16 + grp * 4 + r];
          if (sp < slim)
            kh[(size_t)(((b * H + h) << 10) + sp) * KST + d] =
                (_Float16)(acc[mt][r] + bias);
        }
      }
    }
  } else {
    // V -> [bh][d][sp] via LDS transpose (order-preserving compaction).
    _Float16* sT = (_Float16*)smem;   // 64 x 68 halves = 8704 B (staging free)
    __syncthreads();                  // last mfma done reading sA/sWT
    if (cidx < DIM) {
      const float bias = B[cidx];
      const int colI = cs * 16 + col;
#pragma unroll
      for (int mt = 0; mt < 2; ++mt) {
        const int mtg = mh * 2 + mt;
#pragma unroll
        for (int r = 0; r < 4; ++r)
          sT[colI * 68 + mtg * 16 + grp * 4 + r] = (_Float16)(acc[mt][r] + bias);
      }
    }
    __syncthreads();
    const int sl = tid & 63, cq = tid >> 6;   // cq 0..7
    const int b = row0 >> 10;
    const int sp = sSP[sl];
    if (sp < slim) {
#pragma unroll
      for (int p = 0; p < 8; ++p) {
        const int colI = p * 8 + cq;
        const int c2 = col0 + colI;
        if (c2 < DIM) {
          const int h = c2 / DPH, d = c2 % DPH;
          vth[((size_t)((b * H + h) * DPH + d) << 10) + sp] = sT[colI * 68 + sl];
        }
      }
    }
  }
}

__global__ __launch_bounds__(512, 8) void qkv_kernel(
    const float* __restrict__ x, const float* __restrict__ y,
    const int* __restrict__ mask0, const int* __restrict__ mask1,
    const float* __restrict__ q0w, const float* __restrict__ q0b,
    const float* __restrict__ k0w, const float* __restrict__ k0b,
    const float* __restrict__ v0w, const float* __restrict__ v0b,
    const float* __restrict__ q1w, const float* __restrict__ q1b,
    const float* __restrict__ k1w, const float* __restrict__ k1b,
    const float* __restrict__ v1w, const float* __restrict__ v1b,
    float* __restrict__ ws)
{
  extern __shared__ char smem[];
  _Float16* hws = (_Float16*)ws;
  int* cnts = (int*)(ws + CNT_OFF);
  const int bid = blockIdx.x;
  if (bid < 576)   // 64 mtiles * 3 mats * 3 ntiles
    qkv_impl<192, 16, 12, 3, 3, 12>(bid, x, mask0, q0w, q0b, k0w, k0b, v0w, v0b,
                                    ws + Q0_OFF, hws + 2 * (size_t)K0H_OFF,
                                    hws + 2 * (size_t)V0T_OFF, cnts, smem);
  else             // 64 * 3 * 2 = 384
    qkv_impl<66, 11, 6, 2, 2, 8>(bid - 576, y, mask1, q1w, q1b, k1w, k1b, v1w, v1b,
                                 ws + Q1_OFF, hws + 2 * (size_t)K1H_OFF,
                                 hws + 2 * (size_t)V1T_OFF, cnts + 4, smem);
}

// ---------------------------------------------------------------------------
// Attention (r24: full/tail chunk split) — S^T trick, grid-stride 1024
// blocks over 1728 items. Unchanged.
// ---------------------------------------------------------------------------
template <int H, int DPH, int SKP>
__device__ void attn_impl(int bid, const float* __restrict__ qg,
                          const _Float16* __restrict__ kh,
                          const _Float16* __restrict__ vth,
                          const int* __restrict__ cnts,
                          float* __restrict__ ctx, char* smem)
{
  constexpr int CH = 128;              // keys per chunk
  constexpr int KBUF = CH * SKP + 32;  // +32: kf reads reach key*SKP+15
  constexpr int VST = 136;             // V^T row stride (halves)
  constexpr int DIMQ = H * DPH;

  _Float16* sK = (_Float16*)smem;                 // 2 x KBUF
  _Float16* sVT = sK + 2 * KBUF;                  // 2 x DPH*VST

  const int bh = bid >> 4;             // 16 strips per bh
  const int b = bh / H;
  const int h = bh % H;
  const int tid = threadIdx.x;

  const float* qb_ = qg + ((size_t)b << 10) * DIMQ + h * DPH;  // [b][s][DIM]
  const _Float16* kb_ = kh + (size_t)bh * SLEN * SKP;
  const _Float16* vb_ = vth + ((size_t)bh * DPH << 10);
  const int cnt = cnts[b];
  const int nch = (cnt + CH - 1) >> 7;   // dynamic chunk count (1..8)

  // zero the 32-half tails of both sK buffers (never rewritten by commit)
  if (tid < 64) sK[(tid >> 5) * KBUF + CH * SKP + (tid & 31)] = (_Float16)0.f;

  const int wave = tid >> 6, lane = tid & 63;
  const int col = lane & 15, grp = lane >> 4;
  const int qtile = (bid & 15) * 4 + wave;   // 16-row q-tile index

  // Q fragment, B-operand layout: B[k=d=grp*4+j][n=qrow=col], zero-padded
  f16x4 aq;
  {
    const int qrow = qtile * 16 + col;
#pragma unroll
    for (int j = 0; j < 4; ++j) {
      const int d = grp * 4 + j;
      aq[j] = (d < DPH) ? (_Float16)qb_[(size_t)qrow * DIMQ + d] : (_Float16)0.f;
    }
  }

  // register-staged prefetch / LDS commit
  constexpr int kN = CH * SKP / 8;     // uint4 count for K
  constexpr int vN = DPH * 16;         // uint4 count for V
  const int vd = tid >> 4, vq = tid & 15;
  uint4 pk, pv;
  auto prefetch = [&](int cc) {
    if (tid < kN) pk = ((const uint4*)(kb_ + (size_t)cc * CH * SKP))[tid];
    if (tid < vN) pv = ((const uint4*)(vb_ + ((size_t)vd << 10) + cc * CH))[vq];
  };
  auto commit = [&](int pb) {
    if (tid < kN) ((uint4*)(sK + pb * KBUF))[tid] = pk;
    if (tid < vN) *(uint4*)(sVT + (pb * DPH + vd) * VST + vq * 8) = pv;
  };

  prefetch(0);
  commit(0);
  __syncthreads();

  f32x4 Oacc[2] = {{0.f,0.f,0.f,0.f},{0.f,0.f,0.f,0.f}};
  float lsum = 0.f;
  const int de = (col < DPH) ? col : 0;   // clamped: cols >= DPH discarded

#pragma unroll 1
  for (int c = 0; c < nch; ++c) {
    const int p = c & 1;
    if (c + 1 < nch) prefetch(c + 1);

    const _Float16* sKp = sK + p * KBUF;
    const _Float16* sVp = sVT + p * DPH * VST;

    if (c + 1 < nch) {
      // FULL chunk: every key < cnt -> bias == 0.
#pragma unroll
      for (int kt = 0; kt < CH / 16; ++kt) {
        const f16x4 kf = *(const f16x4*)(sKp + (kt * 16 + col) * SKP + grp * 4);
        const f32x4 z4 = {0.f, 0.f, 0.f, 0.f};
        const f32x4 S = __builtin_amdgcn_mfma_f32_16x16x16f16(kf, aq, z4,
                                                              0, 0, 0);
        const float e0 = EXP2(S[0]), e1 = EXP2(S[1]);
        const float e2 = EXP2(S[2]), e3 = EXP2(S[3]);
        lsum += (e0 + e1) + (e2 + e3);
        const f16x4 pf = {(_Float16)e0, (_Float16)e1, (_Float16)e2, (_Float16)e3};
        const f16x4 vf = *(const f16x4*)(sVp + de * VST + kt * 16 + grp * 4);
        Oacc[kt & 1] = __builtin_amdgcn_mfma_f32_16x16x16f16(pf, vf,
                                                             Oacc[kt & 1],
                                                             0, 0, 0);
      }
    } else {
      // TAIL chunk: per-register -100 bias suppresses keys >= cnt.
      const int keyr = c * CH + grp * 4;
#pragma unroll
      for (int kt = 0; kt < CH / 16; ++kt) {
        const f16x4 kf = *(const f16x4*)(sKp + (kt * 16 + col) * SKP + grp * 4);
        const int k0 = keyr + kt * 16;
        const f32x4 biasv = {(k0 < cnt) ? 0.f : -100.f,
                             (k0 + 1 < cnt) ? 0.f : -100.f,
                             (k0 + 2 < cnt) ? 0.f : -100.f,
                             (k0 + 3 < cnt) ? 0.f : -100.f};
        const f32x4 S = __builtin_amdgcn_mfma_f32_16x16x16f16(kf, aq, biasv,
                                                              0, 0, 0);
        const float e0 = EXP2(S[0]), e1 = EXP2(S[1]);
        const float e2 = EXP2(S[2]), e3 = EXP2(S[3]);
        lsum += (e0 + e1) + (e2 + e3);
        const f16x4 pf = {(_Float16)e0, (_Float16)e1, (_Float16)e2, (_Float16)e3};
        const f16x4 vf = *(const f16x4*)(sVp + de * VST + kt * 16 + grp * 4);
        Oacc[kt & 1] = __builtin_amdgcn_mfma_f32_16x16x16f16(pf, vf,
                                                             Oacc[kt & 1],
                                                             0, 0, 0);
      }
    }

    if (c + 1 < nch) commit(p ^ 1);
    __syncthreads();
  }

  // epilogue — ALL cross-lane ops unconditional (r5's NaN was divergence here)
  f32x4 Osum;
#pragma unroll
  for (int r = 0; r < 4; ++r) Osum[r] = Oacc[0][r] + Oacc[1][r];
  float lred = lsum;
  lred += __shfl_xor(lred, 16);
  lred += __shfl_xor(lred, 32);            // lred = l(qrow=col), all lanes
  float lq[4];
#pragma unroll
  for (int r = 0; r < 4; ++r) lq[r] = __shfl(lred, grp * 4 + r);
  if (col < DPH) {
    const int qrow0 = qtile * 16;
#pragma unroll
    for (int r = 0; r < 4; ++r) {
      const int row = qrow0 + grp * 4 + r;
      ctx[(size_t)(b * SLEN + row) * (H * DPH) + h * DPH + col] = Osum[r] / lq[r];
    }
  }
}

__global__ __launch_bounds__(256) void attn_kernel(float* __restrict__ ws)
{
  extern __shared__ char smem[];
  _Float16* hws = (_Float16*)ws;
  const int* cnts = (const int*)(ws + CNT_OFF);
  const int G = gridDim.x;
#pragma unroll 1
  for (int it = blockIdx.x; it < 1728; it += G) {
    if (it < 1024)  // 64 bh * 16 q-strips
      attn_impl<16, 12, 12>(it, ws + Q0_OFF, hws + 2 * (size_t)K0H_OFF,
                            hws + 2 * (size_t)V0T_OFF, cnts, ws + C0_OFF, smem);
    else             // 44 bh * 16 = 704
      attn_impl<11, 6, 8>(it - 1024, ws + Q1_OFF, hws + 2 * (size_t)K1H_OFF,
                          hws + 2 * (size_t)V1T_OFF, cnts + 4, ws + C1_OFF, smem);
  }
}

// ---------------------------------------------------------------------------
// Output projection (f16 MFMA, 3-term hi/lo split), register-prefetch
// staging; r27: 32-row tiles (MT=2) -> 640 blocks @ 2.5/CU (was 320 @ 1.25).
// Accumulation chains per output element unchanged -> bit-identical.
// ---------------------------------------------------------------------------
template <int DIM, int NCH>
__device__ void oproj_impl(int bid, const float* __restrict__ Cx,
                           const float* __restrict__ ow, const float* __restrict__ ob,
                           float* __restrict__ out, char* smem)
{
  const int mt128 = bid & 127;         // 128 row-tiles of 32 rows
  const int nt = bid >> 7;
  const int row0 = mt128 * 32, col0 = nt * 64;

  _Float16* sAh = (_Float16*)smem;           // 32*72
  _Float16* sAl = sAh + 32 * 72;             // 32*72
  _Float16* sWTh = sAl + 32 * 72;            // 64*72
  _Float16* sWTl = sWTh + 64 * 72;           // 64*72

  const int tid = threadIdx.x;
  const int wv = tid >> 6, lane = tid & 63;

  float2 rA[4], rW[8];
  auto oprefetch = [&](int c) {
    const int kc = c * 64;
#pragma unroll
    for (int t = 0; t < 4; ++t) {
      const int idx = tid + t * 256;
      const int m = idx >> 5, k = (idx & 31) * 2;
      rA[t] = (kc + k < DIM)
                  ? *(const float2*)(Cx + (size_t)(row0 + m) * DIM + kc + k)
                  : make_float2(0.f, 0.f);
    }
#pragma unroll
    for (int t = 0; t < 8; ++t) {
      const int idx = tid + t * 256;
      const int k = idx >> 5, n = (idx & 31) * 2;
      rW[t] = (kc + k < DIM && col0 + n < DIM)
                  ? *(const float2*)(ow + (size_t)(kc + k) * DIM + col0 + n)
                  : make_float2(0.f, 0.f);
    }
  };
  auto ocommit = [&]() {
#pragma unroll
    for (int t = 0; t < 4; ++t) {
      const int idx = tid + t * 256;
      const int m = idx >> 5, k = (idx & 31) * 2;
      const _Float16 hx = (_Float16)rA[t].x, hy = (_Float16)rA[t].y;
      *(f16x2*)(sAh + m * 72 + k) = (f16x2){hx, hy};
      *(f16x2*)(sAl + m * 72 + k) =
          (f16x2){(_Float16)(rA[t].x - (float)hx), (_Float16)(rA[t].y - (float)hy)};
    }
#pragma unroll
    for (int t = 0; t < 8; ++t) {
      const int idx = tid + t * 256;
      const int k = idx >> 5, n = (idx & 31) * 2;
      const _Float16 hx = (_Float16)rW[t].x, hy = (_Float16)rW[t].y;
      sWTh[n * 72 + k] = hx;
      sWTh[(n + 1) * 72 + k] = hy;
      sWTl[n * 72 + k] = (_Float16)(rW[t].x - (float)hx);
      sWTl[(n + 1) * 72 + k] = (_Float16)(rW[t].y - (float)hy);
    }
  };

  oprefetch(0);

  f32x4 acc[2] = {{0.f,0.f,0.f,0.f},{0.f,0.f,0.f,0.f}};

  for (int c = 0; c < NCH; ++c) {
    __syncthreads();
    ocommit();
    __syncthreads();
    if (c + 1 < NCH) oprefetch(c + 1);
    mfma_chunk_split<2>(sAh, sAl, sWTh, sWTl, wv, lane, acc);
  }

  const int col = lane & 15, grp = lane >> 4;
  const int cidx = col0 + wv * 16 + col;
  if (cidx < DIM) {
    const float bias = ob[cidx];
#pragma unroll
    for (int mt = 0; mt < 2; ++mt) {
#pragma unroll
      for (int r = 0; r < 4; ++r) {
        const int m = row0 + mt * 16 + grp * 4 + r;
        out[(size_t)m * DIM + cidx] = acc[mt][r] + bias;
      }
    }
  }
}

__global__ __launch_bounds__(256) void oproj_kernel(
    const float* __restrict__ o0w, const float* __restrict__ o0b,
    const float* __restrict__ o1w, const float* __restrict__ o1b,
    float* __restrict__ ws, float* __restrict__ out)
{
  extern __shared__ char smem[];
  const int bid = blockIdx.x;
  if (bid < 384)   // 128 row-tiles * 3 ntiles
    oproj_impl<192, 3>(bid, ws + C0_OFF, o0w, o0b, out, smem);
  else             // 128 * 2
    oproj_impl<66, 2>(bid - 384, ws + C1_OFF, o1w, o1b, out + OUT0_SIZE, smem);
}

// ---------------------------------------------------------------------------
extern "C" void kernel_launch(void* const* d_in, const int* in_sizes, int n_in,
                              void* d_out, int out_size, void* d_ws, size_t ws_size,
                              hipStream_t stream)
{
  const float* x = (const float*)d_in[0];
  const float* y = (const float*)d_in[1];
  const int* mask0 = (const int*)d_in[2];
  const int* mask1 = (const int*)d_in[3];
  const float* q0w = (const float*)d_in[4];  const float* q0b = (const float*)d_in[5];
  const float* k0w = (const float*)d_in[6];  const float* k0b = (const float*)d_in[7];
  const float* v0w = (const float*)d_in[8];  const float* v0b = (const float*)d_in[9];
  const float* o0w = (const float*)d_in[10]; const float* o0b = (const float*)d_in[11];
  const float* q1w = (const float*)d_in[12]; const float* q1b = (const float*)d_in[13];
  const float* k1w = (const float*)d_in[14]; const float* k1b = (const float*)d_in[15];
  const float* v1w = (const float*)d_in[16]; const float* v1b = (const float*)d_in[17];
  const float* o1w = (const float*)d_in[18]; const float* o1b = (const float*)d_in[19];

  float* ws = (float*)d_ws;
  float* out = (float*)d_out;

  const int qkv_smem = 2 * 64 * 72 * 2 + 72 * 4;           // 18720 B
  const int oproj_smem = (2 * 32 * 72 + 2 * 64 * 72) * 2;  // 27648 B
  // attn: sK 2*(128*12+32)*2 = 6272 + sVT 2*12*136*2 = 6528 -> 12800 B
  const int attn_smem = 2 * (128 * 12 + 32) * 2 + 2 * 12 * 136 * 2;

  qkv_kernel<<<960, 512, qkv_smem, stream>>>(x, y, mask0, mask1,
                                             q0w, q0b, k0w, k0b, v0w, v0b,
                                             q1w, q1b, k1w, k1b, v1w, v1b, ws);
  attn_kernel<<<1024, 256, attn_smem, stream>>>(ws);
  oproj_kernel<<<640, 256, oproj_smem, stream>>>(o0w, o0b, o1w, o1b, ws, out);
}

// Round 17
// 137.865 us; speedup vs baseline: 1.0281x; 1.0281x over previous
//
#include <hip/hip_runtime.h>
#include <math.h>

// Model_7310034338114: two Flaubert/XLM MHA blocks (eval), fp32 in/out.
// inst0: x (4,1024,192), 16 heads, dph=12. inst1: y (4,1024,66), 11 heads, dph=6.
//
// Round 28 = r26 (best, 138.32us; r27's oproj-32 reverted: -3.4us bad) +
// ONE change: qkv epilogue stores -> __builtin_nontemporal_store.
// Key re-derivation: all 960 qkv blocks are CO-RESIDENT (4/CU), so qkv's
// 38us = per-block critical path. Stores add ~33us to EVERY block's chain
// with tiny FETCH/WRITE -> suspect L2 write-allocate/RMW latency on the
// freshly-poisoned (268MB fill) workspace lines. nt stores skip
// write-allocate; data bit-identical; coherence at kernel boundary intact.
// Risk: attn K/V re-reads (x16, ~46MB) lose L2 -> +5-7us; net still a win
// if the mechanism is real.
//
// Lessons ledger: r12 grid.sync ~100us; r14 no cross-XCD fusion/threadfence;
// r15/r16 dispatch/amortization minor; r17 qkv ~40us; r18 conflict/256CUs +
// LDS-occ > barriers; r19 probe confounded by VGPR; r20 store addressing
// null; r21 3->4 blk/CU -1.4; r23 attn 21.6 VALU-bound, oproj 3.5; r24
// bias-split + shuffle-scan null; r25 256thr VGPR64 spill disaster; r26
// 512thr VGPR64 ok, 32 waves/CU -1.6 (occupancy exonerated); r27 oproj-32
// isolated -3.4 (reverted).

#define BS 4
#define SLEN 1024

// workspace float offsets
#define Q0_OFF 0              // f32 [4][1024][192]     (786432)
#define C0_OFF 786432         // f32 [4096][192]        (786432)
#define Q1_OFF 1572864        // f32 [4][1024][66]      (270336)
#define C1_OFF 1843200        // f32 [4096][66]         (270336)
#define K0H_OFF 2113536       // f16 [4][16][1024][12]  (786432 h = 393216 fl)
#define V0T_OFF 2506752       // f16 [4][16][12][1024]  (786432 h)
#define K1H_OFF 2899968       // f16 [4][11][1024][8]   (360448 h = 180224 fl)
#define V1T_OFF 3080192       // f16 [4][11][6][1024]   (270336 h = 135168 fl)
#define CNT_OFF 3223552       // int [8] (inst*4 + b)

#define OUT0_SIZE 786432      // 4096*192

#if __has_builtin(__builtin_amdgcn_exp2f)
#define EXP2(x) __builtin_amdgcn_exp2f(x)
#else
static __device__ __forceinline__ float exp2_asm(float x) {
  float r;
  asm("v_exp_f32 %0, %1" : "=v"(r) : "v"(x));
  return r;
}
#define EXP2(x) exp2_asm(x)
#endif

typedef _Float16 f16x2 __attribute__((ext_vector_type(2)));
typedef _Float16 f16x4 __attribute__((ext_vector_type(4)));
typedef _Float16 f16x8 __attribute__((ext_vector_type(8)));
typedef float f32x4 __attribute__((ext_vector_type(4)));

// ---------------------------------------------------------------------------
// f16-MFMA GEMM building block (hi/lo split), for oproj (r26 64-row tiles).
// ---------------------------------------------------------------------------
__device__ __forceinline__ void mfma_chunk_split(
    const _Float16* sAh, const _Float16* sAl,
    const _Float16* sWTh, const _Float16* sWTl,
    int wv, int lane, f32x4 acc[4])
{
  const int col = lane & 15, grp = lane >> 4;
#pragma unroll
  for (int ks = 0; ks < 2; ++ks) {
    const int boff = (wv * 16 + col) * 72 + ks * 32 + grp * 8;
    const f16x8 bh = *(const f16x8*)(sWTh + boff);
    const f16x8 bl = *(const f16x8*)(sWTl + boff);
#pragma unroll
    for (int mt = 0; mt < 4; ++mt) {
      const int aoff = (mt * 16 + col) * 72 + ks * 32 + grp * 8;
      const f16x8 ah = *(const f16x8*)(sAh + aoff);
      const f16x8 al = *(const f16x8*)(sAl + aoff);
      acc[mt] = __builtin_amdgcn_mfma_f32_16x16x32_f16(ah, bh, acc[mt], 0, 0, 0);
      acc[mt] = __builtin_amdgcn_mfma_f32_16x16x32_f16(ah, bl, acc[mt], 0, 0, 0);
      acc[mt] = __builtin_amdgcn_mfma_f32_16x16x32_f16(al, bh, acc[mt], 0, 0, 0);
    }
  }
}

// ---------------------------------------------------------------------------
// QKV projection + integrated mask scan — 512-thread / 8-wave (r26).
// Wave w: col-strip (w&3), m-half (w>>2); acc[2] per wave.
// r28: epilogue stores are NONTEMPORAL (skip L2 write-allocate).
// ---------------------------------------------------------------------------
template <int DIM, int H, int DPH, int NT, int NCH, int KST>
__device__ void qkv_impl(int bid, const float* __restrict__ X,
                         const int* __restrict__ mask,
                         const float* __restrict__ qw, const float* __restrict__ qb,
                         const float* __restrict__ kw, const float* __restrict__ kb,
                         const float* __restrict__ vw, const float* __restrict__ vb,
                         float* __restrict__ qo, _Float16* __restrict__ kh,
                         _Float16* __restrict__ vth, int* __restrict__ cnt_out,
                         char* smem)
{
  const int mt64 = bid & 63;
  const int rest = bid >> 6;
  const int mat = rest / NT;
  const int nt = rest % NT;
  const int row0 = mt64 * 64, col0 = nt * 64;

  const float* W = (mat == 0) ? qw : (mat == 1) ? kw : vw;
  const float* B = (mat == 0) ? qb : (mat == 1) ? kb : vb;
  const float scale = (mat == 0) ? (1.44269504089f / sqrtf((float)DPH)) : 1.0f;

  _Float16* sA = (_Float16*)smem;            // 64*72 halves
  _Float16* sWT = sA + 64 * 72;              // 64*72 halves
  int* sSP = (int*)(smem + 2 * 64 * 72 * 2); // 64 ints, persists to epilogue
  int* sW8 = sSP + 64;                       // 8 ints (wave scan totals)

  const int tid = threadIdx.x;               // 0..511
  const int wv = tid >> 6, lane = tid & 63;
  const int cs = wv & 3;                     // col strip (0..3)
  const int mh = wv >> 2;                    // m half (0..1)

  // register-staged prefetch (global->reg) / commit (reg->LDS as f16)
  float2 rA[4], rW[4];
  auto qprefetch = [&](int c) {
    const int kc = c * 64;
#pragma unroll
    for (int t = 0; t < 4; ++t) {
      const int idx = tid + t * 512;
      {
        const int m = idx >> 5, k = (idx & 31) * 2;
        rA[t] = (kc + k < DIM)
                    ? *(const float2*)(X + (size_t)(row0 + m) * DIM + kc + k)
                    : make_float2(0.f, 0.f);
      }
      {
        const int k = idx >> 5, n = (idx & 31) * 2;
        rW[t] = (kc + k < DIM && col0 + n < DIM)
                    ? *(const float2*)(W + (size_t)(kc + k) * DIM + col0 + n)
                    : make_float2(0.f, 0.f);
      }
    }
  };
  auto qcommit = [&]() {
#pragma unroll
    for (int t = 0; t < 4; ++t) {
      const int idx = tid + t * 512;
      {
        const int m = idx >> 5, k = (idx & 31) * 2;
        *(f16x2*)(sA + m * 72 + k) = (f16x2){(_Float16)rA[t].x, (_Float16)rA[t].y};
      }
      {
        const int k = idx >> 5, n = (idx & 31) * 2;
        sWT[n * 72 + k] = (_Float16)rW[t].x;
        sWT[(n + 1) * 72 + k] = (_Float16)rW[t].y;
      }
    }
  };

  qprefetch(0);   // issue chunk-0 loads first; scan below runs under their latency

  // ---- in-block mask scan (K/V blocks only): 2 keys/thread, 8-wave combine ----
  int totKV = 0;
  if (mat != 0) {
    const int b = row0 >> 10;
    const int* m = mask + (b << 10);
    int mv[2], s4 = 0;
#pragma unroll
    for (int i = 0; i < 2; ++i) { mv[i] = m[tid * 2 + i] ? 1 : 0; s4 += mv[i]; }
    int ps = s4;                       // wave64 inclusive scan, no barriers
#pragma unroll
    for (int off = 1; off < 64; off <<= 1) {
      const int v = __shfl_up(ps, off);
      if (lane >= off) ps += v;
    }
    if (lane == 63) sW8[wv] = ps;
    __syncthreads();
    int wbase = 0, tot = 0;
#pragma unroll
    for (int w = 0; w < 8; ++w) {
      const int t = sW8[w];
      tot += t;
      if (w < wv) wbase += t;
    }
    totKV = tot;
    int u = wbase + ps - s4;           // exclusive prefix of unmasked count
    const int s0 = row0 & 1023;
#pragma unroll
    for (int i = 0; i < 2; ++i) {
      const int s = tid * 2 + i;
      const int sp = mv[i] ? u : tot + (s - u);
      u += mv[i];
      const unsigned rel = (unsigned)(s - s0);
      if (rel < 64u) sSP[rel] = sp;
    }
    if (mat == 1 && nt == 0 && s0 == 0 && tid == 0) cnt_out[b] = tot;
    __syncthreads();   // sSP visible
  }

  f32x4 acc[2] = {{0.f,0.f,0.f,0.f},{0.f,0.f,0.f,0.f}};
  const int col = lane & 15, grp = lane >> 4;

  for (int c = 0; c < NCH; ++c) {
    __syncthreads();                 // previous mfma done reading LDS
    qcommit();
    __syncthreads();
    if (c + 1 < NCH) qprefetch(c + 1);   // loads overlap this chunk's MFMA
#pragma unroll
    for (int ks = 0; ks < 2; ++ks) {
      const f16x8 bf = *(const f16x8*)(sWT + (cs * 16 + col) * 72 + ks * 32 + grp * 8);
#pragma unroll
      for (int mt = 0; mt < 2; ++mt) {
        const int mtg = mh * 2 + mt;
        const f16x8 af = *(const f16x8*)(sA + (mtg * 16 + col) * 72 + ks * 32 + grp * 8);
        acc[mt] = __builtin_amdgcn_mfma_f32_16x16x32_f16(af, bf, acc[mt], 0, 0, 0);
      }
    }
  }

  const int cidx = col0 + cs * 16 + col;
  const int slim = ((totKV + 127) >> 7) << 7;   // slots >= slim never read

  if (mat == 0) {
    // Q -> [b][s][DIM], nontemporal (no write-allocate).
    if (cidx < DIM) {
      const float bias = B[cidx];
#pragma unroll
      for (int mt = 0; mt < 2; ++mt) {
        const int mtg = mh * 2 + mt;
#pragma unroll
        for (int r = 0; r < 4; ++r) {
          const int m = row0 + mtg * 16 + grp * 4 + r;   // == b*1024 + s
          __builtin_nontemporal_store((acc[mt][r] + bias) * scale,
                                      &qo[(size_t)m * DIM + cidx]);
        }
      }
    }
  } else if (mat == 1) {
    // K -> [bh][sp][KST], nontemporal + dead-slot skip.
    if (cidx < DIM) {
      const float bias = B[cidx];
      const int h = cidx / DPH, d = cidx % DPH;
#pragma unroll
      for (int mt = 0; mt < 2; ++mt) {
        const int mtg = mh * 2 + mt;
#pragma unroll
        for (int r = 0; r < 4; ++r) {
          const int m = row0 + mtg * 16 + grp * 4 + r;
          const int b = m >> 10;
          const int sp = sSP[mtg * 16 + grp * 4 + r];
          if (sp < slim)
            __builtin_nontemporal_store(
                (_Float16)(acc[mt][r] + bias),
                &kh[(size_t)(((b * H + h) << 10) + sp) * KST + d]);
        }
      }
    }
  } else {
    // V -> [bh][d][sp] via LDS transpose, nontemporal stores.
    _Float16* sT = (_Float16*)smem;   // 64 x 68 halves = 8704 B (staging free)
    __syncthreads();                  // last mfma done reading sA/sWT
    if (cidx < DIM) {
      const float bias = B[cidx];
      const int colI = cs * 16 + col;
#pragma unroll
      for (int mt = 0; mt < 2; ++mt) {
        const int mtg = mh * 2 + mt;
#pragma unroll
        for (int r = 0; r < 4; ++r)
          sT[colI * 68 + mtg * 16 + grp * 4 + r] = (_Float16)(acc[mt][r] + bias);
      }
    }
    __syncthreads();
    const int sl = tid & 63, cq = tid >> 6;   // cq 0..7
    const int b = row0 >> 10;
    const int sp = sSP[sl];
    if (sp < slim) {
#pragma unroll
      for (int p = 0; p < 8; ++p) {
        const int colI = p * 8 + cq;
        const int c2 = col0 + colI;
        if (c2 < DIM) {
          const int h = c2 / DPH, d = c2 % DPH;
          __builtin_nontemporal_store(
              sT[colI * 68 + sl],
              &vth[((size_t)((b * H + h) * DPH + d) << 10) + sp]);
        }
      }
    }
  }
}

__global__ __launch_bounds__(512, 8) void qkv_kernel(
    const float* __restrict__ x, const float* __restrict__ y,
    const int* __restrict__ mask0, const int* __restrict__ mask1,
    const float* __restrict__ q0w, const float* __restrict__ q0b,
    const float* __restrict__ k0w, const float* __restrict__ k0b,
    const float* __restrict__ v0w, const float* __restrict__ v0b,
    const float* __restrict__ q1w, const float* __restrict__ q1b,
    const float* __restrict__ k1w, const float* __restrict__ k1b,
    const float* __restrict__ v1w, const float* __restrict__ v1b,
    float* __restrict__ ws)
{
  extern __shared__ char smem[];
  _Float16* hws = (_Float16*)ws;
  int* cnts = (int*)(ws + CNT_OFF);
  const int bid = blockIdx.x;
  if (bid < 576)   // 64 mtiles * 3 mats * 3 ntiles
    qkv_impl<192, 16, 12, 3, 3, 12>(bid, x, mask0, q0w, q0b, k0w, k0b, v0w, v0b,
                                    ws + Q0_OFF, hws + 2 * (size_t)K0H_OFF,
                                    hws + 2 * (size_t)V0T_OFF, cnts, smem);
  else             // 64 * 3 * 2 = 384
    qkv_impl<66, 11, 6, 2, 2, 8>(bid - 576, y, mask1, q1w, q1b, k1w, k1b, v1w, v1b,
                                 ws + Q1_OFF, hws + 2 * (size_t)K1H_OFF,
                                 hws + 2 * (size_t)V1T_OFF, cnts + 4, smem);
}

// ---------------------------------------------------------------------------
// Attention (r24: full/tail chunk split) — S^T trick, grid-stride 1024
// blocks over 1728 items. Unchanged.
// ---------------------------------------------------------------------------
template <int H, int DPH, int SKP>
__device__ void attn_impl(int bid, const float* __restrict__ qg,
                          const _Float16* __restrict__ kh,
                          const _Float16* __restrict__ vth,
                          const int* __restrict__ cnts,
                          float* __restrict__ ctx, char* smem)
{
  constexpr int CH = 128;              // keys per chunk
  constexpr int KBUF = CH * SKP + 32;  // +32: kf reads reach key*SKP+15
  constexpr int VST = 136;             // V^T row stride (halves)
  constexpr int DIMQ = H * DPH;

  _Float16* sK = (_Float16*)smem;                 // 2 x KBUF
  _Float16* sVT = sK + 2 * KBUF;                  // 2 x DPH*VST

  const int bh = bid >> 4;             // 16 strips per bh
  const int b = bh / H;
  const int h = bh % H;
  const int tid = threadIdx.x;

  const float* qb_ = qg + ((size_t)b << 10) * DIMQ + h * DPH;  // [b][s][DIM]
  const _Float16* kb_ = kh + (size_t)bh * SLEN * SKP;
  const _Float16* vb_ = vth + ((size_t)bh * DPH << 10);
  const int cnt = cnts[b];
  const int nch = (cnt + CH - 1) >> 7;   // dynamic chunk count (1..8)

  // zero the 32-half tails of both sK buffers (never rewritten by commit)
  if (tid < 64) sK[(tid >> 5) * KBUF + CH * SKP + (tid & 31)] = (_Float16)0.f;

  const int wave = tid >> 6, lane = tid & 63;
  const int col = lane & 15, grp = lane >> 4;
  const int qtile = (bid & 15) * 4 + wave;   // 16-row q-tile index

  // Q fragment, B-operand layout: B[k=d=grp*4+j][n=qrow=col], zero-padded
  f16x4 aq;
  {
    const int qrow = qtile * 16 + col;
#pragma unroll
    for (int j = 0; j < 4; ++j) {
      const int d = grp * 4 + j;
      aq[j] = (d < DPH) ? (_Float16)qb_[(size_t)qrow * DIMQ + d] : (_Float16)0.f;
    }
  }

  // register-staged prefetch / LDS commit
  constexpr int kN = CH * SKP / 8;     // uint4 count for K
  constexpr int vN = DPH * 16;         // uint4 count for V
  const int vd = tid >> 4, vq = tid & 15;
  uint4 pk, pv;
  auto prefetch = [&](int cc) {
    if (tid < kN) pk = ((const uint4*)(kb_ + (size_t)cc * CH * SKP))[tid];
    if (tid < vN) pv = ((const uint4*)(vb_ + ((size_t)vd << 10) + cc * CH))[vq];
  };
  auto commit = [&](int pb) {
    if (tid < kN) ((uint4*)(sK + pb * KBUF))[tid] = pk;
    if (tid < vN) *(uint4*)(sVT + (pb * DPH + vd) * VST + vq * 8) = pv;
  };

  prefetch(0);
  commit(0);
  __syncthreads();

  f32x4 Oacc[2] = {{0.f,0.f,0.f,0.f},{0.f,0.f,0.f,0.f}};
  float lsum = 0.f;
  const int de = (col < DPH) ? col : 0;   // clamped: cols >= DPH discarded

#pragma unroll 1
  for (int c = 0; c < nch; ++c) {
    const int p = c & 1;
    if (c + 1 < nch) prefetch(c + 1);

    const _Float16* sKp = sK + p * KBUF;
    const _Float16* sVp = sVT + p * DPH * VST;

    if (c + 1 < nch) {
      // FULL chunk: every key < cnt -> bias == 0.
#pragma unroll
      for (int kt = 0; kt < CH / 16; ++kt) {
        const f16x4 kf = *(const f16x4*)(sKp + (kt * 16 + col) * SKP + grp * 4);
        const f32x4 z4 = {0.f, 0.f, 0.f, 0.f};
        const f32x4 S = __builtin_amdgcn_mfma_f32_16x16x16f16(kf, aq, z4,
                                                              0, 0, 0);
        const float e0 = EXP2(S[0]), e1 = EXP2(S[1]);
        const float e2 = EXP2(S[2]), e3 = EXP2(S[3]);
        lsum += (e0 + e1) + (e2 + e3);
        const f16x4 pf = {(_Float16)e0, (_Float16)e1, (_Float16)e2, (_Float16)e3};
        const f16x4 vf = *(const f16x4*)(sVp + de * VST + kt * 16 + grp * 4);
        Oacc[kt & 1] = __builtin_amdgcn_mfma_f32_16x16x16f16(pf, vf,
                                                             Oacc[kt & 1],
                                                             0, 0, 0);
      }
    } else {
      // TAIL chunk: per-register -100 bias suppresses keys >= cnt.
      const int keyr = c * CH + grp * 4;
#pragma unroll
      for (int kt = 0; kt < CH / 16; ++kt) {
        const f16x4 kf = *(const f16x4*)(sKp + (kt * 16 + col) * SKP + grp * 4);
        const int k0 = keyr + kt * 16;
        const f32x4 biasv = {(k0 < cnt) ? 0.f : -100.f,
                             (k0 + 1 < cnt) ? 0.f : -100.f,
                             (k0 + 2 < cnt) ? 0.f : -100.f,
                             (k0 + 3 < cnt) ? 0.f : -100.f};
        const f32x4 S = __builtin_amdgcn_mfma_f32_16x16x16f16(kf, aq, biasv,
                                                              0, 0, 0);
        const float e0 = EXP2(S[0]), e1 = EXP2(S[1]);
        const float e2 = EXP2(S[2]), e3 = EXP2(S[3]);
        lsum += (e0 + e1) + (e2 + e3);
        const f16x4 pf = {(_Float16)e0, (_Float16)e1, (_Float16)e2, (_Float16)e3};
        const f16x4 vf = *(const f16x4*)(sVp + de * VST + kt * 16 + grp * 4);
        Oacc[kt & 1] = __builtin_amdgcn_mfma_f32_16x16x16f16(pf, vf,
                                                             Oacc[kt & 1],
                                                             0, 0, 0);
      }
    }

    if (c + 1 < nch) commit(p ^ 1);
    __syncthreads();
  }

  // epilogue — ALL cross-lane ops unconditional (r5's NaN was divergence here)
  f32x4 Osum;
#pragma unroll
  for (int r = 0; r < 4; ++r) Osum[r] = Oacc[0][r] + Oacc[1][r];
  float lred = lsum;
  lred += __shfl_xor(lred, 16);
  lred += __shfl_xor(lred, 32);            // lred = l(qrow=col), all lanes
  float lq[4];
#pragma unroll
  for (int r = 0; r < 4; ++r) lq[r] = __shfl(lred, grp * 4 + r);
  if (col < DPH) {
    const int qrow0 = qtile * 16;
#pragma unroll
    for (int r = 0; r < 4; ++r) {
      const int row = qrow0 + grp * 4 + r;
      ctx[(size_t)(b * SLEN + row) * (H * DPH) + h * DPH + col] = Osum[r] / lq[r];
    }
  }
}

__global__ __launch_bounds__(256) void attn_kernel(float* __restrict__ ws)
{
  extern __shared__ char smem[];
  _Float16* hws = (_Float16*)ws;
  const int* cnts = (const int*)(ws + CNT_OFF);
  const int G = gridDim.x;
#pragma unroll 1
  for (int it = blockIdx.x; it < 1728; it += G) {
    if (it < 1024)  // 64 bh * 16 q-strips
      attn_impl<16, 12, 12>(it, ws + Q0_OFF, hws + 2 * (size_t)K0H_OFF,
                            hws + 2 * (size_t)V0T_OFF, cnts, ws + C0_OFF, smem);
    else             // 44 bh * 16 = 704
      attn_impl<11, 6, 8>(it - 1024, ws + Q1_OFF, hws + 2 * (size_t)K1H_OFF,
                          hws + 2 * (size_t)V1T_OFF, cnts + 4, ws + C1_OFF, smem);
  }
}

// ---------------------------------------------------------------------------
// Output projection (f16 MFMA, 3-term hi/lo split => ~fp32 accuracy), with
// register-prefetch staging (r26: 64-row tiles, 320 blocks — r27 reverted).
// ---------------------------------------------------------------------------
template <int DIM, int NCH>
__device__ void oproj_impl(int bid, const float* __restrict__ Cx,
                           const float* __restrict__ ow, const float* __restrict__ ob,
                           float* __restrict__ out, char* smem)
{
  const int mt64 = bid & 63;
  const int nt = bid >> 6;
  const int row0 = mt64 * 64, col0 = nt * 64;

  _Float16* sAh = (_Float16*)smem;
  _Float16* sAl = sAh + 64 * 72;
  _Float16* sWTh = sAl + 64 * 72;
  _Float16* sWTl = sWTh + 64 * 72;

  const int tid = threadIdx.x;
  const int wv = tid >> 6, lane = tid & 63;

  float2 rA[8], rW[8];
  auto oprefetch = [&](int c) {
    const int kc = c * 64;
#pragma unroll
    for (int t = 0; t < 8; ++t) {
      const int idx = tid + t * 256;
      {
        const int m = idx >> 5, k = (idx & 31) * 2;
        rA[t] = (kc + k < DIM)
                    ? *(const float2*)(Cx + (size_t)(row0 + m) * DIM + kc + k)
                    : make_float2(0.f, 0.f);
      }
      {
        const int k = idx >> 5, n = (idx & 31) * 2;
        rW[t] = (kc + k < DIM && col0 + n < DIM)
                    ? *(const float2*)(ow + (size_t)(kc + k) * DIM + col0 + n)
                    : make_float2(0.f, 0.f);
      }
    }
  };
  auto ocommit = [&]() {
#pragma unroll
    for (int t = 0; t < 8; ++t) {
      const int idx = tid + t * 256;
      {
        const int m = idx >> 5, k = (idx & 31) * 2;
        const _Float16 hx = (_Float16)rA[t].x, hy = (_Float16)rA[t].y;
        *(f16x2*)(sAh + m * 72 + k) = (f16x2){hx, hy};
        *(f16x2*)(sAl + m * 72 + k) =
            (f16x2){(_Float16)(rA[t].x - (float)hx), (_Float16)(rA[t].y - (float)hy)};
      }
      {
        const int k = idx >> 5, n = (idx & 31) * 2;
        const _Float16 hx = (_Float16)rW[t].x, hy = (_Float16)rW[t].y;
        sWTh[n * 72 + k] = hx;
        sWTh[(n + 1) * 72 + k] = hy;
        sWTl[n * 72 + k] = (_Float16)(rW[t].x - (float)hx);
        sWTl[(n + 1) * 72 + k] = (_Float16)(rW[t].y - (float)hy);
      }
    }
  };

  oprefetch(0);

  f32x4 acc[4] = {{0.f,0.f,0.f,0.f},{0.f,0.f,0.f,0.f},{0.f,0.f,0.f,0.f},{0.f,0.f,0.f,0.f}};

  for (int c = 0; c < NCH; ++c) {
    __syncthreads();
    ocommit();
    __syncthreads();
    if (c + 1 < NCH) oprefetch(c + 1);
    mfma_chunk_split(sAh, sAl, sWTh, sWTl, wv, lane, acc);
  }

  const int col = lane & 15, grp = lane >> 4;
  const int cidx = col0 + wv * 16 + col;
  if (cidx < DIM) {
    const float bias = ob[cidx];
#pragma unroll
    for (int mt = 0; mt < 4; ++mt) {
#pragma unroll
      for (int r = 0; r < 4; ++r) {
        const int m = row0 + mt * 16 + grp * 4 + r;
        out[(size_t)m * DIM + cidx] = acc[mt][r] + bias;
      }
    }
  }
}

__global__ __launch_bounds__(256) void oproj_kernel(
    const float* __restrict__ o0w, const float* __restrict__ o0b,
    const float* __restrict__ o1w, const float* __restrict__ o1b,
    float* __restrict__ ws, float* __restrict__ out)
{
  extern __shared__ char smem[];
  const int bid = blockIdx.x;
  if (bid < 192)
    oproj_impl<192, 3>(bid, ws + C0_OFF, o0w, o0b, out, smem);
  else
    oproj_impl<66, 2>(bid - 192, ws + C1_OFF, o1w, o1b, out + OUT0_SIZE, smem);
}

// ---------------------------------------------------------------------------
extern "C" void kernel_launch(void* const* d_in, const int* in_sizes, int n_in,
                              void* d_out, int out_size, void* d_ws, size_t ws_size,
                              hipStream_t stream)
{
  const float* x = (const float*)d_in[0];
  const float* y = (const float*)d_in[1];
  const int* mask0 = (const int*)d_in[2];
  const int* mask1 = (const int*)d_in[3];
  const float* q0w = (const float*)d_in[4];  const float* q0b = (const float*)d_in[5];
  const float* k0w = (const float*)d_in[6];  const float* k0b = (const float*)d_in[7];
  const float* v0w = (const float*)d_in[8];  const float* v0b = (const float*)d_in[9];
  const float* o0w = (const float*)d_in[10]; const float* o0b = (const float*)d_in[11];
  const float* q1w = (const float*)d_in[12]; const float* q1b = (const float*)d_in[13];
  const float* k1w = (const float*)d_in[14]; const float* k1b = (const float*)d_in[15];
  const float* v1w = (const float*)d_in[16]; const float* v1b = (const float*)d_in[17];
  const float* o1w = (const float*)d_in[18]; const float* o1b = (const float*)d_in[19];

  float* ws = (float*)d_ws;
  float* out = (float*)d_out;

  const int qkv_smem = 2 * 64 * 72 * 2 + 72 * 4;   // 18720 B
  const int oproj_smem = 4 * 64 * 72 * 2;          // 36864 B
  // attn: sK 2*(128*12+32)*2 = 6272 + sVT 2*12*136*2 = 6528 -> 12800 B
  const int attn_smem = 2 * (128 * 12 + 32) * 2 + 2 * 12 * 136 * 2;

  qkv_kernel<<<960, 512, qkv_smem, stream>>>(x, y, mask0, mask1,
                                             q0w, q0b, k0w, k0b, v0w, v0b,
                                             q1w, q1b, k1w, k1b, v1w, v1b, ws);
  attn_kernel<<<1024, 256, attn_smem, stream>>>(ws);
  oproj_kernel<<<320, 256, oproj_smem, stream>>>(o0w, o0b, o1w, o1b, ws, out);
}